// Round 13
// baseline (315.638 us; speedup 1.0000x reference)
//
#include <hip/hip_runtime.h>
#include <hip/hip_bf16.h>
#include <cstdint>

// ---------------------------------------------------------------------------
// TempoSpikeSelfAttention on MI355X (gfx950), bf16-MFMA pipeline.  v10
//   dims: T=4 B=4 N=1024 D=768 H=12 Dh=64 -> M = T*B*N = 16384 rows
// v10 changes (vs v9, 303.1 us measured; QKV GEMM 99.4 us / MfmaUtil 24%):
//   * NEW gemm256 for the QKV GEMM: 256x256 tile, 8 waves (2Mx4N), BK=32,
//     64 KB LDS (2 dbuf x (A 256x32 + B 256x32)), phase-pipelined K-loop
//     (4 phases/K-tile, one C-quadrant each), counted vmcnt(2) once per
//     K-tile (never 0 mid-loop), setprio around MFMA, XOR LDS swizzle
//     (col ^= (row&6)*4 el, involution applied to stage-source AND read).
//     Staging stream per K-tile t: {A0(t+1),A1(t+1),B0(t+2),B1(t+2)} at
//     phases 0..3; each target dead >=1 closed phase earlier (B(t) dead
//     after ph0, A(t) after ph3, A(t+1) is the other dbuf).
//     vmcnt FIFO trace: prologue 6 issued, vmcnt(2) -> tile0 resident;
//     steady state 4/iter -> 6 at close -> vmcnt(2) leaves B(t+2) in flight.
//   * O GEMM stays on the 128^2 gemm_bt (N=768 -> 256^2 underfills).
// Pipeline:
//   1. cast_all; 2. gemm256 QKV (bias fused, V written transposed to Vt);
//   3. attn32 (v9 double-buffer, lgkm-only barrier); 4. gemm_bt O.
// ---------------------------------------------------------------------------

typedef __attribute__((ext_vector_type(8))) short short8;     // 8 bf16 = 4 VGPR
typedef __attribute__((ext_vector_type(4))) float float4v;    // 16x16 acc
typedef __attribute__((ext_vector_type(16))) float float16v;  // 32x32 acc

__device__ __forceinline__ unsigned short f2bf(float f) {
  unsigned int u = __float_as_uint(f);
  u = (u + 0x7fffu + ((u >> 16) & 1u)) >> 16;   // RNE
  return (unsigned short)u;
}

__device__ __forceinline__ unsigned int pkbf(float a, float b) {
  unsigned int ua = __float_as_uint(a) + 0x8000u;
  unsigned int ub = __float_as_uint(b) + 0x8000u;
  return __builtin_amdgcn_perm(ub, ua, 0x07060302u);  // [bf(a) lo16 | bf(b) hi16]
}

__device__ __forceinline__ void gld_lds16(const void* g, void* lds) {
  __builtin_amdgcn_global_load_lds(
      (__attribute__((address_space(1))) void*)(uintptr_t)g,
      (__attribute__((address_space(3))) void*)(uint32_t)(uintptr_t)lds,
      16, 0, 0);
}

// ---------------------------------------------------------------------------
__global__ __launch_bounds__(256) void cast_all(
    const float* __restrict__ x,  const float* __restrict__ Wq,
    const float* __restrict__ Wk, const float* __restrict__ Wv,
    const float* __restrict__ Wo, unsigned short* __restrict__ XBF,
    unsigned short* __restrict__ WQKV, unsigned short* __restrict__ WOb) {
  const int bid = blockIdx.x;
  const float* src;
  unsigned short* dst;
  int i;
  if (bid < 12288) {
    src = x; dst = XBF; i = bid * 256 + threadIdx.x;
  } else {
    const int wb = bid - 12288;          // 0..2303
    const int which = wb / 576;
    i = (wb % 576) * 256 + threadIdx.x;  // < 147456
    src = (which == 0) ? Wq : (which == 1) ? Wk : (which == 2) ? Wv : Wo;
    dst = (which == 0) ? WQKV
        : (which == 1) ? WQKV + 589824
        : (which == 2) ? WQKV + 1179648 : WOb;
  }
  float4 f = reinterpret_cast<const float4*>(src)[i];
  ushort4 o;
  o.x = f2bf(f.x); o.y = f2bf(f.y); o.z = f2bf(f.z); o.w = f2bf(f.w);
  reinterpret_cast<ushort4*>(dst)[i] = o;
}

// ---------------------------------------------------------------------------
// QKV GEMM, 256x256 tile, 512 thr = 8 waves (2Mx4N), BK=32, K=768 (24 tiles).
// Per wave: 128x64 output = 8x4 frags (16x16x32), acc = 128 VGPR.
// Phase p (=quadrant q): ds_read A fm{2q,2q+1} (+ all B at p0) -> stage one
// half-tile -> s_barrier -> lgkmcnt(0) -> setprio(1) 8 MFMA setprio(0)
// [-> vmcnt(2) at p3] -> s_barrier.
// LDS swizzle: LDS[r][c] = global[r][c ^ ((r&6)*4)] (elements); read with the
// same XOR -> <=4-way banks (linear layout would be 8-16-way).
__global__ __launch_bounds__(512) void gemm256(
    const unsigned short* __restrict__ A,   // [16384, 768] bf16
    const unsigned short* __restrict__ Bt,  // [2304, 768]  bf16 (WQKV)
    unsigned short* __restrict__ Cb,        // QKV [16384, 2304] bf16
    unsigned short* __restrict__ Vt,        // [(tb*12+h)*64+d][1024] bf16
    const float* __restrict__ b0, const float* __restrict__ b1,
    const float* __restrict__ b2) {
  constexpr int K = 768;
  constexpr int KT = 24;                        // K / 32
  __shared__ unsigned short Ab[2][256 * 32];    // 16 KB per buf
  __shared__ unsigned short Bb[2][256 * 32];    // total 64 KB

  const int tid = threadIdx.x;
  const int lane = tid & 63;
  const int wv = tid >> 6;                 // 0..7
  const int wm = wv >> 2, wn = wv & 3;     // 2 x 4 wave grid
  const int l15 = lane & 15, quad = lane >> 4;

  // bijective XCD swizzle over 9x64 = 576 blocks (%8 == 0)
  const int gx = gridDim.x;                // 9
  const int nwg = gx * gridDim.y;          // 576
  const int hw = blockIdx.y * gx + blockIdx.x;
  const int per = nwg >> 3;
  const int lg = (hw & 7) * per + (hw >> 3);
  const int bx = lg % gx, by = lg / gx;
  const int i0 = by * 256, j0 = bx * 256;

  // staging: 512 thr cover one half-tile (128 rows x 32 el) per call,
  // 1 x 16B chunk per thread. Source col pre-XORed (inverse swizzle).
  const int srow = tid >> 2;                                    // 0..127
  const int scol = ((tid & 3) << 3) ^ ((srow & 6) << 2);        // 8-el aligned
  const unsigned short* pa0 = A  + (size_t)(i0 + srow) * K + scol;
  const unsigned short* pb0 = Bt + (size_t)(j0 + srow) * K + scol;
  // LDS read offsets (elements), same XOR on the read side
  const int xsw = ((quad * 8) ^ ((l15 & 6) * 4));
  const int aoff = (wm * 128 + l15) * 32 + xsw;
  const int boff = (wn * 64 + l15) * 32 + xsw;

  auto stA = [&](int kt, int bb, int h) {
    gld_lds16(pa0 + (size_t)h * 128 * K + kt * 32,
              &Ab[bb][h * 4096 + wv * 512]);
  };
  auto stB = [&](int kt, int bb, int h) {
    gld_lds16(pb0 + (size_t)h * 128 * K + kt * 32,
              &Bb[bb][h * 4096 + wv * 512]);
  };

  float4v acc[8][4];
#pragma unroll
  for (int m = 0; m < 8; ++m)
#pragma unroll
    for (int n = 0; n < 4; ++n) acc[m][n] = float4v{0.f, 0.f, 0.f, 0.f};

  // prologue: K-tile 0 (4 half-tiles) + B(1) (2 half-tiles); wait first 4.
  stB(0, 0, 0); stB(0, 0, 1);
  stA(0, 0, 0); stA(0, 0, 1);
  stB(1, 1, 0); stB(1, 1, 1);
  asm volatile("s_waitcnt vmcnt(2)" ::: "memory");
  __builtin_amdgcn_s_barrier();
  __builtin_amdgcn_sched_barrier(0);

#pragma unroll 1
  for (int t = 0; t < KT; ++t) {
    const int bb = t & 1, nb = bb ^ 1;
    short8 bf[4];
    short8 a0, a1;

    // ---- phase 0: quadrant fm{0,1}; reads all B(t); stage A0(t+1) ----
#pragma unroll
    for (int fn = 0; fn < 4; ++fn)
      bf[fn] = *(const short8*)&Bb[bb][boff + fn * 512];
    a0 = *(const short8*)&Ab[bb][aoff + 0 * 512];
    a1 = *(const short8*)&Ab[bb][aoff + 1 * 512];
    if (t + 1 < KT) stA(t + 1, nb, 0);
    __builtin_amdgcn_s_barrier();
    asm volatile("s_waitcnt lgkmcnt(0)" ::: "memory");
    __builtin_amdgcn_sched_barrier(0);
    __builtin_amdgcn_s_setprio(1);
#pragma unroll
    for (int fn = 0; fn < 4; ++fn)
      acc[0][fn] = __builtin_amdgcn_mfma_f32_16x16x32_bf16(a0, bf[fn], acc[0][fn], 0, 0, 0);
#pragma unroll
    for (int fn = 0; fn < 4; ++fn)
      acc[1][fn] = __builtin_amdgcn_mfma_f32_16x16x32_bf16(a1, bf[fn], acc[1][fn], 0, 0, 0);
    __builtin_amdgcn_s_setprio(0);
    __builtin_amdgcn_s_barrier();

    // ---- phase 1: fm{2,3}; stage A1(t+1) ----
    a0 = *(const short8*)&Ab[bb][aoff + 2 * 512];
    a1 = *(const short8*)&Ab[bb][aoff + 3 * 512];
    if (t + 1 < KT) stA(t + 1, nb, 1);
    __builtin_amdgcn_s_barrier();
    asm volatile("s_waitcnt lgkmcnt(0)" ::: "memory");
    __builtin_amdgcn_sched_barrier(0);
    __builtin_amdgcn_s_setprio(1);
#pragma unroll
    for (int fn = 0; fn < 4; ++fn)
      acc[2][fn] = __builtin_amdgcn_mfma_f32_16x16x32_bf16(a0, bf[fn], acc[2][fn], 0, 0, 0);
#pragma unroll
    for (int fn = 0; fn < 4; ++fn)
      acc[3][fn] = __builtin_amdgcn_mfma_f32_16x16x32_bf16(a1, bf[fn], acc[3][fn], 0, 0, 0);
    __builtin_amdgcn_s_setprio(0);
    __builtin_amdgcn_s_barrier();

    // ---- phase 2: fm{4,5}; stage B0(t+2) (B(t) LDS dead since ph0 close) --
    a0 = *(const short8*)&Ab[bb][aoff + 4 * 512];
    a1 = *(const short8*)&Ab[bb][aoff + 5 * 512];
    if (t + 2 < KT) stB(t + 2, bb, 0);
    __builtin_amdgcn_s_barrier();
    asm volatile("s_waitcnt lgkmcnt(0)" ::: "memory");
    __builtin_amdgcn_sched_barrier(0);
    __builtin_amdgcn_s_setprio(1);
#pragma unroll
    for (int fn = 0; fn < 4; ++fn)
      acc[4][fn] = __builtin_amdgcn_mfma_f32_16x16x32_bf16(a0, bf[fn], acc[4][fn], 0, 0, 0);
#pragma unroll
    for (int fn = 0; fn < 4; ++fn)
      acc[5][fn] = __builtin_amdgcn_mfma_f32_16x16x32_bf16(a1, bf[fn], acc[5][fn], 0, 0, 0);
    __builtin_amdgcn_s_setprio(0);
    __builtin_amdgcn_s_barrier();

    // ---- phase 3: fm{6,7}; stage B1(t+2); counted vmcnt; close ----
    a0 = *(const short8*)&Ab[bb][aoff + 6 * 512];
    a1 = *(const short8*)&Ab[bb][aoff + 7 * 512];
    if (t + 2 < KT) stB(t + 2, bb, 1);
    __builtin_amdgcn_s_barrier();
    asm volatile("s_waitcnt lgkmcnt(0)" ::: "memory");
    __builtin_amdgcn_sched_barrier(0);
    __builtin_amdgcn_s_setprio(1);
#pragma unroll
    for (int fn = 0; fn < 4; ++fn)
      acc[6][fn] = __builtin_amdgcn_mfma_f32_16x16x32_bf16(a0, bf[fn], acc[6][fn], 0, 0, 0);
#pragma unroll
    for (int fn = 0; fn < 4; ++fn)
      acc[7][fn] = __builtin_amdgcn_mfma_f32_16x16x32_bf16(a1, bf[fn], acc[7][fn], 0, 0, 0);
    __builtin_amdgcn_s_setprio(0);
    // drain tile t+1 (4 oldest half-tiles); keep B(t+2)'s 2 loads in flight
    if (t + 2 < KT) {
      asm volatile("s_waitcnt vmcnt(2)" ::: "memory");
      __builtin_amdgcn_s_barrier();
      __builtin_amdgcn_sched_barrier(0);
    } else if (t + 1 < KT) {
      asm volatile("s_waitcnt vmcnt(0)" ::: "memory");
      __builtin_amdgcn_s_barrier();
      __builtin_amdgcn_sched_barrier(0);
    }
    // t == KT-1: no trailing barrier; epilogue is register-only
  }

  // ---- epilogue: sel is block-uniform (768 = 3 * 256) ----
  const int sel = bx / 3;
  const float* bp = (sel == 0) ? b0 : ((sel == 1) ? b1 : b2);
#pragma unroll
  for (int fm = 0; fm < 8; ++fm) {
    const int row0 = i0 + wm * 128 + fm * 16 + quad * 4;
#pragma unroll
    for (int fn = 0; fn < 4; ++fn) {
      const int col = j0 + wn * 64 + fn * 16 + l15;
      const float bias = bp[col - sel * 768];
      if (sel == 2) {
        // V block -> transposed store into Vt
        const int tb = row0 >> 10;
        const int n0 = row0 & 1023;          // multiple of 4 -> 8B aligned
        const int hd = col - 1536;           // h*64 + d
        const float v0 = acc[fm][fn][0] + bias;
        const float v1 = acc[fm][fn][1] + bias;
        const float v2 = acc[fm][fn][2] + bias;
        const float v3 = acc[fm][fn][3] + bias;
        uint2 u;
        u.x = (unsigned int)f2bf(v0) | ((unsigned int)f2bf(v1) << 16);
        u.y = (unsigned int)f2bf(v2) | ((unsigned int)f2bf(v3) << 16);
        *(uint2*)&Vt[((size_t)(tb * 768 + hd)) * 1024 + n0] = u;
      } else {
#pragma unroll
        for (int r = 0; r < 4; ++r)
          Cb[(size_t)(row0 + r) * 2304 + col] = f2bf(acc[fm][fn][r] + bias);
      }
    }
  }
}

// ---------------------------------------------------------------------------
// O GEMM: 128x128 tile, 3-buffer counted-vmcnt (v7 structure, measured).
__global__ __launch_bounds__(256) void gemm_bt(
    const unsigned short* __restrict__ A,   // [M,768] bf16
    const unsigned short* __restrict__ Bt,  // [N,768] bf16
    float* __restrict__ Cf,                 // f32 out  [M,N]
    const float* __restrict__ b0, int N) {
  constexpr int K = 768;
  constexpr int KT = K / 32;                   // 24 K-tiles
  __shared__ unsigned short As[3][128 * 32];   // row stride 32 el (64 B)
  __shared__ unsigned short Bs[3][128 * 32];

  const int tid = threadIdx.x;
  const int lane = tid & 63;
  const int w = tid >> 6;
  const int wrow = w >> 1, wcol = w & 1;
  const int l15 = lane & 15, quad = lane >> 4;

  const int gx = gridDim.x;
  const int nwg = gx * gridDim.y;                   // 768; % 8 == 0
  const int hw = blockIdx.y * gx + blockIdx.x;
  const int per = nwg >> 3;
  const int lg = (hw & 7) * per + (hw >> 3);
  const int bx = lg % gx, by = lg / gx;
  const int i0 = by * 128, j0 = bx * 128;

  const unsigned short* ga = A + (size_t)(i0 + 32 * w + (lane >> 2)) * K + (lane & 3) * 8;
  const unsigned short* gb = Bt + (size_t)(j0 + 32 * w + (lane >> 2)) * K + (lane & 3) * 8;

  auto stage = [&](int kt2, int bufi) {
    const unsigned short* pa = ga + kt2 * 32;
    const unsigned short* pb = gb + kt2 * 32;
    gld_lds16(pa, &As[bufi][(32 * w) * 32]);
    gld_lds16(pa + 16 * K, &As[bufi][(32 * w + 16) * 32]);
    gld_lds16(pb, &Bs[bufi][(32 * w) * 32]);
    gld_lds16(pb + 16 * K, &Bs[bufi][(32 * w + 16) * 32]);
  };

  float4v acc[4][4];
#pragma unroll
  for (int a = 0; a < 4; ++a)
#pragma unroll
    for (int b = 0; b < 4; ++b) acc[a][b] = float4v{0.f, 0.f, 0.f, 0.f};

  stage(0, 0);
  stage(1, 1);
  asm volatile("s_waitcnt vmcnt(4)" ::: "memory");
  __builtin_amdgcn_s_barrier();
  __builtin_amdgcn_sched_barrier(0);

#pragma unroll 1
  for (int kt = 0; kt < KT; ++kt) {
    const int cur = kt % 3;
    if (kt + 2 < KT) stage(kt + 2, (kt + 2) % 3);

    short8 af[4], bfr[4];
#pragma unroll
    for (int a = 0; a < 4; ++a)
      af[a] = *(const short8*)&As[cur][(wrow * 64 + a * 16 + l15) * 32 + quad * 8];
#pragma unroll
    for (int b = 0; b < 4; ++b)
      bfr[b] = *(const short8*)&Bs[cur][(wcol * 64 + b * 16 + l15) * 32 + quad * 8];
#pragma unroll
    for (int a = 0; a < 4; ++a)
#pragma unroll
      for (int b = 0; b < 4; ++b)
        acc[a][b] = __builtin_amdgcn_mfma_f32_16x16x32_bf16(af[a], bfr[b], acc[a][b], 0, 0, 0);

    if (kt + 2 < KT) {
      asm volatile("s_waitcnt vmcnt(4)" ::: "memory");
      __builtin_amdgcn_s_barrier();
      __builtin_amdgcn_sched_barrier(0);
    } else if (kt + 1 < KT) {
      asm volatile("s_waitcnt vmcnt(0)" ::: "memory");
      __builtin_amdgcn_s_barrier();
      __builtin_amdgcn_sched_barrier(0);
    }
  }

#pragma unroll
  for (int a = 0; a < 4; ++a) {
    const int row0 = i0 + wrow * 64 + a * 16 + quad * 4;
#pragma unroll
    for (int b = 0; b < 4; ++b) {
      const int col = j0 + wcol * 64 + b * 16 + l15;
      const float bias = b0[col];
#pragma unroll
      for (int r = 0; r < 4; ++r)
        Cf[(size_t)(row0 + r) * N + col] = acc[a][b][r] + bias;
    }
  }
}

// ---------------------------------------------------------------------------
// Attention v9 (measured good): double-buffered K/V LDS, one lgkm-only
// barrier per kv-tile; loads kv+1 in flight across barrier + compute.
__global__ __launch_bounds__(256) void attn32(
    const unsigned short* __restrict__ qkv,  // [16384, 2304] bf16
    const unsigned short* __restrict__ vt,   // [(tbh)*64 + d][1024] bf16
    unsigned short* __restrict__ ctx) {      // [16384, 768] bf16
  __shared__ unsigned short Ks[2][64 * 72];  // [buf][kv_local][d], padded
  __shared__ unsigned short Vs[2][64 * 72];  // [buf][d][kv_local], padded

  const int tbh = blockIdx.x;
  const int qt = blockIdx.y;
  const int tb = tbh / 12, h = tbh % 12;
  const int tid = threadIdx.x, lane = tid & 63, w = tid >> 6;
  const int l31 = lane & 31, hl = lane >> 5;

  short8 qf[2][4];
#pragma unroll
  for (int qs = 0; qs < 2; ++qs) {
    const unsigned short* qp =
        qkv + (size_t)(tb * 1024 + qt * 256 + w * 64 + qs * 32 + l31) * 2304 +
        h * 64 + hl * 8;
#pragma unroll
    for (int kc = 0; kc < 4; ++kc) qf[qs][kc] = *(const short8*)(qp + kc * 16);
  }

  const int srow = tid >> 3;   // 0..31 (and +32)
  const int sblk = tid & 7;
  const unsigned short* kcol =
      qkv + (size_t)(tb * 1024) * 2304 + 768 + h * 64 + sblk * 8;
  const unsigned short* vcol = vt + ((size_t)tbh * 64 + srow) * 1024 + sblk * 8;
  uint4 kr0, kr1, vr0, vr1;
  auto loadKV = [&](int kv) {
    const unsigned short* kp = kcol + (size_t)(kv * 64 + srow) * 2304;
    kr0 = *(const uint4*)kp;
    kr1 = *(const uint4*)(kp + 32 * 2304);
    const unsigned short* vp = vcol + kv * 64;
    vr0 = *(const uint4*)vp;
    vr1 = *(const uint4*)(vp + 32 * 1024);
  };

  float16v octx[2][2];
#pragma unroll
  for (int qs = 0; qs < 2; ++qs)
#pragma unroll
    for (int dt = 0; dt < 2; ++dt)
#pragma unroll
      for (int i = 0; i < 16; ++i) octx[qs][dt][i] = 0.f;
  float den[2] = {0.f, 0.f};

  loadKV(0);

#pragma unroll 1
  for (int kv = 0; kv < 16; ++kv) {
    const int cur = kv & 1;
    *(uint4*)&Ks[cur][srow * 72 + sblk * 8] = kr0;
    *(uint4*)&Ks[cur][(srow + 32) * 72 + sblk * 8] = kr1;
    *(uint4*)&Vs[cur][srow * 72 + sblk * 8] = vr0;
    *(uint4*)&Vs[cur][(srow + 32) * 72 + sblk * 8] = vr1;
    if (kv < 15) loadKV(kv + 1);
    asm volatile("s_waitcnt lgkmcnt(0)" ::: "memory");
    __builtin_amdgcn_s_barrier();
    __builtin_amdgcn_sched_barrier(0);

#pragma unroll
    for (int qs = 0; qs < 2; ++qs) {
      unsigned int pk[2][8];
#pragma unroll
      for (int mt = 0; mt < 2; ++mt) {
        float16v st;
#pragma unroll
        for (int i = 0; i < 16; ++i) st[i] = 0.f;
#pragma unroll
        for (int kc = 0; kc < 4; ++kc) {
          short8 kf =
              *(const short8*)&Ks[cur][(mt * 32 + l31) * 72 + kc * 16 + hl * 8];
          st = __builtin_amdgcn_mfma_f32_32x32x16_bf16(kf, qf[qs][kc], st, 0, 0, 0);
        }
#pragma unroll
        for (int g = 0; g < 4; ++g) {
          float v0 = st[4 * g + 0]; v0 = v0 > 0.f ? v0 : 0.f;
          float v1 = st[4 * g + 1]; v1 = v1 > 0.f ? v1 : 0.f;
          float v2 = st[4 * g + 2]; v2 = v2 > 0.f ? v2 : 0.f;
          float v3 = st[4 * g + 3]; v3 = v3 > 0.f ? v3 : 0.f;
          den[qs] += (v0 + v1) + (v2 + v3);
          pk[mt][g * 2 + 0] = pkbf(v0, v1);
          pk[mt][g * 2 + 1] = pkbf(v2, v3);
        }
      }
#pragma unroll
      for (int kc = 0; kc < 4; ++kc) {
        const int mt = kc >> 1, gb = (kc & 1) * 2;
        unsigned int a0 = pk[mt][gb * 2 + 0], b0 = pk[mt][gb * 2 + 2];
        unsigned int a1 = pk[mt][gb * 2 + 1], b1 = pk[mt][gb * 2 + 3];
        asm("v_permlane32_swap_b32 %0, %1" : "+v"(a0), "+v"(b0));
        asm("v_permlane32_swap_b32 %0, %1" : "+v"(a1), "+v"(b1));
        union { unsigned int u[4]; short8 s; } pf;
        pf.u[0] = a0; pf.u[1] = a1; pf.u[2] = b0; pf.u[3] = b1;
#pragma unroll
        for (int dt = 0; dt < 2; ++dt) {
          short8 vb =
              *(const short8*)&Vs[cur][(dt * 32 + l31) * 72 + kc * 16 + hl * 8];
          octx[qs][dt] = __builtin_amdgcn_mfma_f32_32x32x16_bf16(
              vb, pf.s, octx[qs][dt], 0, 0, 0);
        }
      }
    }
  }

#pragma unroll
  for (int qs = 0; qs < 2; ++qs) {
    float d = den[qs] + __shfl_xor(den[qs], 32);
    const float sc = 1.f / (d + 8e-6f);   // folded 1/sqrt(64) scaling
    const size_t qrow = (size_t)(tb * 1024 + qt * 256 + w * 64 + qs * 32 + l31);
#pragma unroll
    for (int dt = 0; dt < 2; ++dt)
#pragma unroll
      for (int g = 0; g < 4; ++g) {
        const float v0 = octx[qs][dt][4 * g + 0] * sc;
        const float v1 = octx[qs][dt][4 * g + 1] * sc;
        const float v2 = octx[qs][dt][4 * g + 2] * sc;
        const float v3 = octx[qs][dt][4 * g + 3] * sc;
        uint2 u;
        u.x = pkbf(v0, v1);
        u.y = pkbf(v2, v3);
        *(uint2*)&ctx[qrow * 768 + h * 64 + dt * 32 + g * 8 + hl * 4] = u;
      }
  }
}

// ---------------------------------------------------------------------------
extern "C" void kernel_launch(void* const* d_in, const int* in_sizes, int n_in,
                              void* d_out, int out_size, void* d_ws, size_t ws_size,
                              hipStream_t stream) {
  const float* x  = (const float*)d_in[0];
  const float* Wq = (const float*)d_in[1];
  const float* bq = (const float*)d_in[2];
  const float* Wk = (const float*)d_in[3];
  const float* bk = (const float*)d_in[4];
  const float* Wv = (const float*)d_in[5];
  const float* bv = (const float*)d_in[6];
  const float* Wo = (const float*)d_in[7];
  const float* bo = (const float*)d_in[8];
  float* out = (float*)d_out;

  char* ws = (char*)d_ws;
  unsigned short* XBF  = (unsigned short*)(ws);                  // 25165824 B
  unsigned short* CTX  = (unsigned short*)(ws);                  // alias
  unsigned short* WQKV = (unsigned short*)(ws + 25165824);       //  3538944 B
  unsigned short* WOb  = (unsigned short*)(ws + 28704768);       //  1179648 B
  unsigned short* QKV  = (unsigned short*)(ws + 29884416);       // 75497472 B
  unsigned short* VT   = (unsigned short*)(ws + 105381888);      // 25165824 B

  cast_all<<<14592, 256, 0, stream>>>(x, Wq, Wk, Wv, Wo, XBF, WQKV, WOb);

  gemm256<<<dim3(9, 64), 512, 0, stream>>>(XBF, WQKV, QKV, VT, bq, bk, bv);
  attn32<<<dim3(192, 4), 256, 0, stream>>>(QKV, VT, CTX);
  gemm_bt<<<dim3(6, 128), 256, 0, stream>>>(CTX, WOb, out, bo, 768);
}

// Round 16
// 308.411 us; speedup vs baseline: 1.0234x; 1.0234x over previous
//
#include <hip/hip_runtime.h>
#include <hip/hip_bf16.h>
#include <cstdint>

// ---------------------------------------------------------------------------
// TempoSpikeSelfAttention on MI355X (gfx950), bf16-MFMA pipeline.  v11
//   dims: T=4 B=4 N=1024 D=768 H=12 Dh=64 -> M = T*B*N = 16384 rows
// v11 changes (vs v10, 315.6 us; gemm256 103 us, MfmaUtil 23%, all pipes idle):
//   * gemm256 BK 32 -> 64 (m201-faithful): 16 MFMA per phase (was 8), 96
//     barrier-pairs total (was 192), LDS 128 KB (1 block/CU like m201).
//     v10's failure was phase granularity: 8 MFMA (~40cyc) per 2 barriers ->
//     sync overhead dominated (MfmaUtil 23 / VALU 16 / HBM 16 all idle).
//   * Swizzle re-derived for 64-el rows: stage source col ^= (row&7)*8 el;
//     read slot (ks*4+quad) ^ (l15&7). 16-way -> 2-way (free).
//   * vmcnt ledger: steady close outstanding [A(t+1)x4, B(t+2)x4] ->
//     vmcnt(4) drains A(t+1), leaves B(t+2). Prologue: B(0)4 A(0)4 B(1)4
//     -> vmcnt(4) drains tile 0. Tail t=KT-2 -> vmcnt(0).
// Pipeline: cast_all; gemm256 QKV (bias fused, V transposed to Vt);
//           attn32 (v9); gemm_bt O (v7 structure).
// ---------------------------------------------------------------------------

typedef __attribute__((ext_vector_type(8))) short short8;     // 8 bf16 = 4 VGPR
typedef __attribute__((ext_vector_type(4))) float float4v;    // 16x16 acc
typedef __attribute__((ext_vector_type(16))) float float16v;  // 32x32 acc

__device__ __forceinline__ unsigned short f2bf(float f) {
  unsigned int u = __float_as_uint(f);
  u = (u + 0x7fffu + ((u >> 16) & 1u)) >> 16;   // RNE
  return (unsigned short)u;
}

__device__ __forceinline__ unsigned int pkbf(float a, float b) {
  unsigned int ua = __float_as_uint(a) + 0x8000u;
  unsigned int ub = __float_as_uint(b) + 0x8000u;
  return __builtin_amdgcn_perm(ub, ua, 0x07060302u);  // [bf(a) lo16 | bf(b) hi16]
}

__device__ __forceinline__ void gld_lds16(const void* g, void* lds) {
  __builtin_amdgcn_global_load_lds(
      (__attribute__((address_space(1))) void*)(uintptr_t)g,
      (__attribute__((address_space(3))) void*)(uint32_t)(uintptr_t)lds,
      16, 0, 0);
}

// ---------------------------------------------------------------------------
__global__ __launch_bounds__(256) void cast_all(
    const float* __restrict__ x,  const float* __restrict__ Wq,
    const float* __restrict__ Wk, const float* __restrict__ Wv,
    const float* __restrict__ Wo, unsigned short* __restrict__ XBF,
    unsigned short* __restrict__ WQKV, unsigned short* __restrict__ WOb) {
  const int bid = blockIdx.x;
  const float* src;
  unsigned short* dst;
  int i;
  if (bid < 12288) {
    src = x; dst = XBF; i = bid * 256 + threadIdx.x;
  } else {
    const int wb = bid - 12288;          // 0..2303
    const int which = wb / 576;
    i = (wb % 576) * 256 + threadIdx.x;  // < 147456
    src = (which == 0) ? Wq : (which == 1) ? Wk : (which == 2) ? Wv : Wo;
    dst = (which == 0) ? WQKV
        : (which == 1) ? WQKV + 589824
        : (which == 2) ? WQKV + 1179648 : WOb;
  }
  float4 f = reinterpret_cast<const float4*>(src)[i];
  ushort4 o;
  o.x = f2bf(f.x); o.y = f2bf(f.y); o.z = f2bf(f.z); o.w = f2bf(f.w);
  reinterpret_cast<ushort4*>(dst)[i] = o;
}

// ---------------------------------------------------------------------------
// QKV GEMM, 256x256 tile, 512 thr = 8 waves (2Mx4N), BK=64, K=768 (12 tiles).
// Per wave: 128x64 output = 8x4 frags; per phase: one fm-pair quadrant x
// (4 fn x 2 ks) = 16 MFMA. B frags (8) read once per tile at ph0, held in
// regs. LDS: Ab/Bb 2buf x 256x64 el = 128 KB total -> 1 block/CU.
// Stage call = 64 rows x 64 el (8 KB, 512 thr x 16B); 4 calls per operand
// tile. Source col pre-XORed by (row&7)*8 el; read slot (ks*4+quad)^(l15&7).
__global__ __launch_bounds__(512) void gemm256(
    const unsigned short* __restrict__ A,   // [16384, 768] bf16
    const unsigned short* __restrict__ Bt,  // [2304, 768]  bf16 (WQKV)
    unsigned short* __restrict__ Cb,        // QKV [16384, 2304] bf16
    unsigned short* __restrict__ Vt,        // [(tb*12+h)*64+d][1024] bf16
    const float* __restrict__ b0, const float* __restrict__ b1,
    const float* __restrict__ b2) {
  constexpr int K = 768;
  constexpr int KT = 12;                        // K / 64
  __shared__ unsigned short Ab[2][256 * 64];    // 32 KB per buf
  __shared__ unsigned short Bb[2][256 * 64];    // total 128 KB

  const int tid = threadIdx.x;
  const int lane = tid & 63;
  const int wv = tid >> 6;                 // 0..7
  const int wm = wv >> 2, wn = wv & 3;     // 2 x 4 wave grid
  const int l15 = lane & 15, quad = lane >> 4;
  const int xr = l15 & 7;                  // read-side XOR (slot units)

  // bijective XCD swizzle over 9x64 = 576 blocks (%8 == 0)
  const int gx = gridDim.x;                // 9
  const int nwg = gx * gridDim.y;          // 576
  const int hw = blockIdx.y * gx + blockIdx.x;
  const int per = nwg >> 3;
  const int lg = (hw & 7) * per + (hw >> 3);
  const int bx = lg % gx, by = lg / gx;
  const int i0 = by * 256, j0 = bx * 256;

  // staging: call = 64 rows x 64 el; thread: row = tid>>3, chunk = tid&7.
  // LDS dest linear (base + lane*8 el); swizzle lives in the SOURCE col.
  const int srow = tid >> 3;                                   // 0..63
  const int scol = ((tid & 7) * 8) ^ ((srow & 7) * 8);
  const unsigned short* pa0 = A  + (size_t)(i0 + srow) * K + scol;
  const unsigned short* pb0 = Bt + (size_t)(j0 + srow) * K + scol;

  auto stA = [&](int kt, int bb_, int h) {   // h = 0..3: 64-row quarter
    gld_lds16(pa0 + (size_t)h * 64 * K + kt * 64,
              &Ab[bb_][h * 4096 + wv * 512]);
  };
  auto stB = [&](int kt, int bb_, int h) {
    gld_lds16(pb0 + (size_t)h * 64 * K + kt * 64,
              &Bb[bb_][h * 4096 + wv * 512]);
  };

  float4v acc[8][4];
#pragma unroll
  for (int m = 0; m < 8; ++m)
#pragma unroll
    for (int n = 0; n < 4; ++n) acc[m][n] = float4v{0.f, 0.f, 0.f, 0.f};

  // prologue: B(0) A(0) B(1); drain the first 8 -> tile 0 resident.
  stB(0, 0, 0); stB(0, 0, 1); stB(0, 0, 2); stB(0, 0, 3);
  stA(0, 0, 0); stA(0, 0, 1); stA(0, 0, 2); stA(0, 0, 3);
  stB(1, 1, 0); stB(1, 1, 1); stB(1, 1, 2); stB(1, 1, 3);
  asm volatile("s_waitcnt vmcnt(4)" ::: "memory");
  __builtin_amdgcn_s_barrier();
  __builtin_amdgcn_sched_barrier(0);

#pragma unroll 1
  for (int t = 0; t < KT; ++t) {
    const int bb_ = t & 1, nb = bb_ ^ 1;
    short8 bfq[4][2];

#pragma unroll
    for (int p = 0; p < 4; ++p) {
      short8 a0[2], a1[2];
#pragma unroll
      for (int ks = 0; ks < 2; ++ks) {
        if (p == 0) {
#pragma unroll
          for (int fn = 0; fn < 4; ++fn)
            bfq[fn][ks] = *(const short8*)
                &Bb[bb_][(wn * 64 + fn * 16 + l15) * 64 +
                         (((ks * 4 + quad) ^ xr) * 8)];
        }
        a0[ks] = *(const short8*)
            &Ab[bb_][(wm * 128 + (2 * p) * 16 + l15) * 64 +
                     (((ks * 4 + quad) ^ xr) * 8)];
        a1[ks] = *(const short8*)
            &Ab[bb_][(wm * 128 + (2 * p + 1) * 16 + l15) * 64 +
                     (((ks * 4 + quad) ^ xr) * 8)];
      }
      // staging stream: ph0-1 -> A(t+1) into other buf; ph2-3 -> B(t+2)
      // into SAME buf (B(t) LDS dead since ph0-close).
      if (p < 2) {
        if (t + 1 < KT) { stA(t + 1, nb, 2 * p); stA(t + 1, nb, 2 * p + 1); }
      } else {
        if (t + 2 < KT) { stB(t + 2, bb_, 2 * (p - 2)); stB(t + 2, bb_, 2 * (p - 2) + 1); }
      }
      __builtin_amdgcn_s_barrier();
      asm volatile("s_waitcnt lgkmcnt(0)" ::: "memory");
      __builtin_amdgcn_sched_barrier(0);
      __builtin_amdgcn_s_setprio(1);
#pragma unroll
      for (int ks = 0; ks < 2; ++ks) {
#pragma unroll
        for (int fn = 0; fn < 4; ++fn) {
          acc[2 * p][fn] = __builtin_amdgcn_mfma_f32_16x16x32_bf16(
              a0[ks], bfq[fn][ks], acc[2 * p][fn], 0, 0, 0);
          acc[2 * p + 1][fn] = __builtin_amdgcn_mfma_f32_16x16x32_bf16(
              a1[ks], bfq[fn][ks], acc[2 * p + 1][fn], 0, 0, 0);
        }
      }
      __builtin_amdgcn_s_setprio(0);
      if (p < 3) {
        __builtin_amdgcn_s_barrier();
      } else {
        // close: drain A(t+1); keep B(t+2)'s 4 loads in flight
        if (t + 2 < KT) {
          asm volatile("s_waitcnt vmcnt(4)" ::: "memory");
          __builtin_amdgcn_s_barrier();
          __builtin_amdgcn_sched_barrier(0);
        } else if (t + 1 < KT) {
          asm volatile("s_waitcnt vmcnt(0)" ::: "memory");
          __builtin_amdgcn_s_barrier();
          __builtin_amdgcn_sched_barrier(0);
        }
        // t == KT-1: no trailing barrier; epilogue register-only
      }
    }
  }

  // ---- epilogue: sel is block-uniform (768 = 3 * 256) ----
  const int sel = bx / 3;
  const float* bp = (sel == 0) ? b0 : ((sel == 1) ? b1 : b2);
#pragma unroll
  for (int fm = 0; fm < 8; ++fm) {
    const int row0 = i0 + wm * 128 + fm * 16 + quad * 4;
#pragma unroll
    for (int fn = 0; fn < 4; ++fn) {
      const int col = j0 + wn * 64 + fn * 16 + l15;
      const float bias = bp[col - sel * 768];
      if (sel == 2) {
        // V block -> transposed store into Vt
        const int tb = row0 >> 10;
        const int n0 = row0 & 1023;          // multiple of 4 -> 8B aligned
        const int hd = col - 1536;           // h*64 + d
        const float v0 = acc[fm][fn][0] + bias;
        const float v1 = acc[fm][fn][1] + bias;
        const float v2 = acc[fm][fn][2] + bias;
        const float v3 = acc[fm][fn][3] + bias;
        uint2 u;
        u.x = (unsigned int)f2bf(v0) | ((unsigned int)f2bf(v1) << 16);
        u.y = (unsigned int)f2bf(v2) | ((unsigned int)f2bf(v3) << 16);
        *(uint2*)&Vt[((size_t)(tb * 768 + hd)) * 1024 + n0] = u;
      } else {
#pragma unroll
        for (int r = 0; r < 4; ++r)
          Cb[(size_t)(row0 + r) * 2304 + col] = f2bf(acc[fm][fn][r] + bias);
      }
    }
  }
}

// ---------------------------------------------------------------------------
// O GEMM: 128x128 tile, 3-buffer counted-vmcnt (v7 structure, measured).
__global__ __launch_bounds__(256) void gemm_bt(
    const unsigned short* __restrict__ A,   // [M,768] bf16
    const unsigned short* __restrict__ Bt,  // [N,768] bf16
    float* __restrict__ Cf,                 // f32 out  [M,N]
    const float* __restrict__ b0, int N) {
  constexpr int K = 768;
  constexpr int KT = K / 32;                   // 24 K-tiles
  __shared__ unsigned short As[3][128 * 32];   // row stride 32 el (64 B)
  __shared__ unsigned short Bs[3][128 * 32];

  const int tid = threadIdx.x;
  const int lane = tid & 63;
  const int w = tid >> 6;
  const int wrow = w >> 1, wcol = w & 1;
  const int l15 = lane & 15, quad = lane >> 4;

  const int gx = gridDim.x;
  const int nwg = gx * gridDim.y;                   // 768; % 8 == 0
  const int hw = blockIdx.y * gx + blockIdx.x;
  const int per = nwg >> 3;
  const int lg = (hw & 7) * per + (hw >> 3);
  const int bx = lg % gx, by = lg / gx;
  const int i0 = by * 128, j0 = bx * 128;

  const unsigned short* ga = A + (size_t)(i0 + 32 * w + (lane >> 2)) * K + (lane & 3) * 8;
  const unsigned short* gb = Bt + (size_t)(j0 + 32 * w + (lane >> 2)) * K + (lane & 3) * 8;

  auto stage = [&](int kt2, int bufi) {
    const unsigned short* pa = ga + kt2 * 32;
    const unsigned short* pb = gb + kt2 * 32;
    gld_lds16(pa, &As[bufi][(32 * w) * 32]);
    gld_lds16(pa + 16 * K, &As[bufi][(32 * w + 16) * 32]);
    gld_lds16(pb, &Bs[bufi][(32 * w) * 32]);
    gld_lds16(pb + 16 * K, &Bs[bufi][(32 * w + 16) * 32]);
  };

  float4v acc[4][4];
#pragma unroll
  for (int a = 0; a < 4; ++a)
#pragma unroll
    for (int b = 0; b < 4; ++b) acc[a][b] = float4v{0.f, 0.f, 0.f, 0.f};

  stage(0, 0);
  stage(1, 1);
  asm volatile("s_waitcnt vmcnt(4)" ::: "memory");
  __builtin_amdgcn_s_barrier();
  __builtin_amdgcn_sched_barrier(0);

#pragma unroll 1
  for (int kt = 0; kt < KT; ++kt) {
    const int cur = kt % 3;
    if (kt + 2 < KT) stage(kt + 2, (kt + 2) % 3);

    short8 af[4], bfr[4];
#pragma unroll
    for (int a = 0; a < 4; ++a)
      af[a] = *(const short8*)&As[cur][(wrow * 64 + a * 16 + l15) * 32 + quad * 8];
#pragma unroll
    for (int b = 0; b < 4; ++b)
      bfr[b] = *(const short8*)&Bs[cur][(wcol * 64 + b * 16 + l15) * 32 + quad * 8];
#pragma unroll
    for (int a = 0; a < 4; ++a)
#pragma unroll
      for (int b = 0; b < 4; ++b)
        acc[a][b] = __builtin_amdgcn_mfma_f32_16x16x32_bf16(af[a], bfr[b], acc[a][b], 0, 0, 0);

    if (kt + 2 < KT) {
      asm volatile("s_waitcnt vmcnt(4)" ::: "memory");
      __builtin_amdgcn_s_barrier();
      __builtin_amdgcn_sched_barrier(0);
    } else if (kt + 1 < KT) {
      asm volatile("s_waitcnt vmcnt(0)" ::: "memory");
      __builtin_amdgcn_s_barrier();
      __builtin_amdgcn_sched_barrier(0);
    }
  }

#pragma unroll
  for (int a = 0; a < 4; ++a) {
    const int row0 = i0 + wrow * 64 + a * 16 + quad * 4;
#pragma unroll
    for (int b = 0; b < 4; ++b) {
      const int col = j0 + wcol * 64 + b * 16 + l15;
      const float bias = b0[col];
#pragma unroll
      for (int r = 0; r < 4; ++r)
        Cf[(size_t)(row0 + r) * N + col] = acc[a][b][r] + bias;
    }
  }
}

// ---------------------------------------------------------------------------
// Attention v9 (measured good): double-buffered K/V LDS, one lgkm-only
// barrier per kv-tile; loads kv+1 in flight across barrier + compute.
__global__ __launch_bounds__(256) void attn32(
    const unsigned short* __restrict__ qkv,  // [16384, 2304] bf16
    const unsigned short* __restrict__ vt,   // [(tbh)*64 + d][1024] bf16
    unsigned short* __restrict__ ctx) {      // [16384, 768] bf16
  __shared__ unsigned short Ks[2][64 * 72];  // [buf][kv_local][d], padded
  __shared__ unsigned short Vs[2][64 * 72];  // [buf][d][kv_local], padded

  const int tbh = blockIdx.x;
  const int qt = blockIdx.y;
  const int tb = tbh / 12, h = tbh % 12;
  const int tid = threadIdx.x, lane = tid & 63, w = tid >> 6;
  const int l31 = lane & 31, hl = lane >> 5;

  short8 qf[2][4];
#pragma unroll
  for (int qs = 0; qs < 2; ++qs) {
    const unsigned short* qp =
        qkv + (size_t)(tb * 1024 + qt * 256 + w * 64 + qs * 32 + l31) * 2304 +
        h * 64 + hl * 8;
#pragma unroll
    for (int kc = 0; kc < 4; ++kc) qf[qs][kc] = *(const short8*)(qp + kc * 16);
  }

  const int srow = tid >> 3;   // 0..31 (and +32)
  const int sblk = tid & 7;
  const unsigned short* kcol =
      qkv + (size_t)(tb * 1024) * 2304 + 768 + h * 64 + sblk * 8;
  const unsigned short* vcol = vt + ((size_t)tbh * 64 + srow) * 1024 + sblk * 8;
  uint4 kr0, kr1, vr0, vr1;
  auto loadKV = [&](int kv) {
    const unsigned short* kp = kcol + (size_t)(kv * 64 + srow) * 2304;
    kr0 = *(const uint4*)kp;
    kr1 = *(const uint4*)(kp + 32 * 2304);
    const unsigned short* vp = vcol + kv * 64;
    vr0 = *(const uint4*)vp;
    vr1 = *(const uint4*)(vp + 32 * 1024);
  };

  float16v octx[2][2];
#pragma unroll
  for (int qs = 0; qs < 2; ++qs)
#pragma unroll
    for (int dt = 0; dt < 2; ++dt)
#pragma unroll
      for (int i = 0; i < 16; ++i) octx[qs][dt][i] = 0.f;
  float den[2] = {0.f, 0.f};

  loadKV(0);

#pragma unroll 1
  for (int kv = 0; kv < 16; ++kv) {
    const int cur = kv & 1;
    *(uint4*)&Ks[cur][srow * 72 + sblk * 8] = kr0;
    *(uint4*)&Ks[cur][(srow + 32) * 72 + sblk * 8] = kr1;
    *(uint4*)&Vs[cur][srow * 72 + sblk * 8] = vr0;
    *(uint4*)&Vs[cur][(srow + 32) * 72 + sblk * 8] = vr1;
    if (kv < 15) loadKV(kv + 1);
    asm volatile("s_waitcnt lgkmcnt(0)" ::: "memory");
    __builtin_amdgcn_s_barrier();
    __builtin_amdgcn_sched_barrier(0);

#pragma unroll
    for (int qs = 0; qs < 2; ++qs) {
      unsigned int pk[2][8];
#pragma unroll
      for (int mt = 0; mt < 2; ++mt) {
        float16v st;
#pragma unroll
        for (int i = 0; i < 16; ++i) st[i] = 0.f;
#pragma unroll
        for (int kc = 0; kc < 4; ++kc) {
          short8 kf =
              *(const short8*)&Ks[cur][(mt * 32 + l31) * 72 + kc * 16 + hl * 8];
          st = __builtin_amdgcn_mfma_f32_32x32x16_bf16(kf, qf[qs][kc], st, 0, 0, 0);
        }
#pragma unroll
        for (int g = 0; g < 4; ++g) {
          float v0 = st[4 * g + 0]; v0 = v0 > 0.f ? v0 : 0.f;
          float v1 = st[4 * g + 1]; v1 = v1 > 0.f ? v1 : 0.f;
          float v2 = st[4 * g + 2]; v2 = v2 > 0.f ? v2 : 0.f;
          float v3 = st[4 * g + 3]; v3 = v3 > 0.f ? v3 : 0.f;
          den[qs] += (v0 + v1) + (v2 + v3);
          pk[mt][g * 2 + 0] = pkbf(v0, v1);
          pk[mt][g * 2 + 1] = pkbf(v2, v3);
        }
      }
#pragma unroll
      for (int kc = 0; kc < 4; ++kc) {
        const int mt = kc >> 1, gb = (kc & 1) * 2;
        unsigned int a0 = pk[mt][gb * 2 + 0], b0 = pk[mt][gb * 2 + 2];
        unsigned int a1 = pk[mt][gb * 2 + 1], b1 = pk[mt][gb * 2 + 3];
        asm("v_permlane32_swap_b32 %0, %1" : "+v"(a0), "+v"(b0));
        asm("v_permlane32_swap_b32 %0, %1" : "+v"(a1), "+v"(b1));
        union { unsigned int u[4]; short8 s; } pf;
        pf.u[0] = a0; pf.u[1] = a1; pf.u[2] = b0; pf.u[3] = b1;
#pragma unroll
        for (int dt = 0; dt < 2; ++dt) {
          short8 vb =
              *(const short8*)&Vs[cur][(dt * 32 + l31) * 72 + kc * 16 + hl * 8];
          octx[qs][dt] = __builtin_amdgcn_mfma_f32_32x32x16_bf16(
              vb, pf.s, octx[qs][dt], 0, 0, 0);
        }
      }
    }
  }

#pragma unroll
  for (int qs = 0; qs < 2; ++qs) {
    float d = den[qs] + __shfl_xor(den[qs], 32);
    const float sc = 1.f / (d + 8e-6f);   // folded 1/sqrt(64) scaling
    const size_t qrow = (size_t)(tb * 1024 + qt * 256 + w * 64 + qs * 32 + l31);
#pragma unroll
    for (int dt = 0; dt < 2; ++dt)
#pragma unroll
      for (int g = 0; g < 4; ++g) {
        const float v0 = octx[qs][dt][4 * g + 0] * sc;
        const float v1 = octx[qs][dt][4 * g + 1] * sc;
        const float v2 = octx[qs][dt][4 * g + 2] * sc;
        const float v3 = octx[qs][dt][4 * g + 3] * sc;
        uint2 u;
        u.x = pkbf(v0, v1);
        u.y = pkbf(v2, v3);
        *(uint2*)&ctx[qrow * 768 + h * 64 + dt * 32 + g * 8 + hl * 4] = u;
      }
  }
}

// ---------------------------------------------------------------------------
extern "C" void kernel_launch(void* const* d_in, const int* in_sizes, int n_in,
                              void* d_out, int out_size, void* d_ws, size_t ws_size,
                              hipStream_t stream) {
  const float* x  = (const float*)d_in[0];
  const float* Wq = (const float*)d_in[1];
  const float* bq = (const float*)d_in[2];
  const float* Wk = (const float*)d_in[3];
  const float* bk = (const float*)d_in[4];
  const float* Wv = (const float*)d_in[5];
  const float* bv = (const float*)d_in[6];
  const float* Wo = (const float*)d_in[7];
  const float* bo = (const float*)d_in[8];
  float* out = (float*)d_out;

  char* ws = (char*)d_ws;
  unsigned short* XBF  = (unsigned short*)(ws);                  // 25165824 B
  unsigned short* CTX  = (unsigned short*)(ws);                  // alias
  unsigned short* WQKV = (unsigned short*)(ws + 25165824);       //  3538944 B
  unsigned short* WOb  = (unsigned short*)(ws + 28704768);       //  1179648 B
  unsigned short* QKV  = (unsigned short*)(ws + 29884416);       // 75497472 B
  unsigned short* VT   = (unsigned short*)(ws + 105381888);      // 25165824 B

  cast_all<<<14592, 256, 0, stream>>>(x, Wq, Wk, Wv, Wo, XBF, WQKV, WOb);

  gemm256<<<dim3(9, 64), 512, 0, stream>>>(XBF, WQKV, QKV, VT, bq, bk, bv);
  attn32<<<dim3(192, 4), 256, 0, stream>>>(QKV, VT, CTX);
  gemm_bt<<<dim3(6, 128), 256, 0, stream>>>(CTX, WOb, out, bo, 768);
}

// Round 17
// 303.410 us; speedup vs baseline: 1.0403x; 1.0165x over previous
//
#include <hip/hip_runtime.h>
#include <hip/hip_bf16.h>
#include <cstdint>

// ---------------------------------------------------------------------------
// TempoSpikeSelfAttention on MI355X (gfx950), bf16-MFMA pipeline.  v12
//   dims: T=4 B=4 N=1024 D=768 H=12 Dh=64 -> M = T*B*N = 16384 rows
// v12 = v9 (303.1 us, best measured total) + attn32 cvt_pk VALU reduction.
//   * REVERT gemm256 (8-phase lane abandoned: BK32=103us, BK64=94us, both
//     MfmaUtil ~24% and total WORSE than v9's gemm_bt 99.4us pipeline -
//     at K=768 / 576-block grid the phase overhead + tail quantization
//     dominates; per r15 pre-commitment the lane is closed).
//   * attn32: pkbf (2 add + 1 perm = 3 VALU) pairs -> single inline-asm
//     v_cvt_pk_bf16_f32 (1 VALU, RNE). r8 counters: attn VALUBusy 41.5 vs
//     MfmaUtil 19.3 - VALU-bound; P-pack path per g drops 14->10 ops.
// Pipeline:
//   1. cast_all: x, Wq|Wk|Wv (concat), Wo -> bf16 (one dispatch)
//   2. QKV GEMM gemm_bt<true> (3-buf counted-vmcnt, 128^2): bias fused;
//      V column-blocks written TRANSPOSED straight to Vt
//   3. attn32 (v9 dbuf, lgkm-only barrier; cvt_pk pack)
//   4. O GEMM gemm_bt<false> -> fp32 out
// ---------------------------------------------------------------------------

typedef __attribute__((ext_vector_type(8))) short short8;     // 8 bf16 = 4 VGPR
typedef __attribute__((ext_vector_type(4))) float float4v;    // 16x16 acc
typedef __attribute__((ext_vector_type(16))) float float16v;  // 32x32 acc

__device__ __forceinline__ unsigned short f2bf(float f) {
  unsigned int u = __float_as_uint(f);
  u = (u + 0x7fffu + ((u >> 16) & 1u)) >> 16;   // RNE
  return (unsigned short)u;
}

// pack two f32 -> two bf16 (round-half-away) in one v_perm_b32
__device__ __forceinline__ unsigned int pkbf(float a, float b) {
  unsigned int ua = __float_as_uint(a) + 0x8000u;
  unsigned int ub = __float_as_uint(b) + 0x8000u;
  return __builtin_amdgcn_perm(ub, ua, 0x07060302u);  // [bf(a) lo16 | bf(b) hi16]
}

// pack two f32 -> two bf16 (RNE) in ONE VALU op (no builtin on gfx950)
__device__ __forceinline__ unsigned int cvtpk(float lo, float hi) {
  unsigned int r;
  asm("v_cvt_pk_bf16_f32 %0, %1, %2" : "=v"(r) : "v"(lo), "v"(hi));
  return r;   // [bf(lo) lo16 | bf(hi) hi16]
}

// async global->LDS, 16B per lane; LDS dest = wave-uniform base + lane*16
__device__ __forceinline__ void gld_lds16(const void* g, void* lds) {
  __builtin_amdgcn_global_load_lds(
      (__attribute__((address_space(1))) void*)(uintptr_t)g,
      (__attribute__((address_space(3))) void*)(uint32_t)(uintptr_t)lds,
      16, 0, 0);
}

// ---------------------------------------------------------------------------
// One dispatch for all fp32->bf16 casts. Block-uniform routing:
//   blocks [0,12288)        : x   (3145728 float4)
//   blocks [12288,12288+576): Wq -> WQKV[0]
//   next 576                : Wk -> WQKV+589824
//   next 576                : Wv -> WQKV+1179648
//   next 576                : Wo -> WOb
__global__ __launch_bounds__(256) void cast_all(
    const float* __restrict__ x,  const float* __restrict__ Wq,
    const float* __restrict__ Wk, const float* __restrict__ Wv,
    const float* __restrict__ Wo, unsigned short* __restrict__ XBF,
    unsigned short* __restrict__ WQKV, unsigned short* __restrict__ WOb) {
  const int bid = blockIdx.x;
  const float* src;
  unsigned short* dst;
  int i;
  if (bid < 12288) {
    src = x; dst = XBF; i = bid * 256 + threadIdx.x;
  } else {
    const int wb = bid - 12288;          // 0..2303
    const int which = wb / 576;
    i = (wb % 576) * 256 + threadIdx.x;  // < 147456
    src = (which == 0) ? Wq : (which == 1) ? Wk : (which == 2) ? Wv : Wo;
    dst = (which == 0) ? WQKV
        : (which == 1) ? WQKV + 589824
        : (which == 2) ? WQKV + 1179648 : WOb;
  }
  float4 f = reinterpret_cast<const float4*>(src)[i];
  ushort4 o;
  o.x = f2bf(f.x); o.y = f2bf(f.y); o.z = f2bf(f.z); o.w = f2bf(f.w);
  reinterpret_cast<ushort4*>(dst)[i] = o;
}

// ---------------------------------------------------------------------------
// C[i,j] = sum_k A[i,k] * Bt[j,k] + bias[j].  K=768 fixed. 128x128 tile, BK=32.
// 4 waves in 2x2, each 64x64 (4x4 mfma 16x16x32 tiles).
// 3-buffer 2-deep pipeline, counted vmcnt (never 0 in steady state).
// OUT_BF16 path: column-blocks with sel==2 (V) are written TRANSPOSED to Vt.
template <bool OUT_BF16>
__global__ __launch_bounds__(256) void gemm_bt(
    const unsigned short* __restrict__ A,   // [M,768] bf16
    const unsigned short* __restrict__ Bt,  // [N,768] bf16
    unsigned short* __restrict__ Cb,        // bf16 out [M,N]
    float* __restrict__ Cf,                 // f32 out  [M,N]
    unsigned short* __restrict__ Vt,        // bf16 out [(tb*12+h)*64+d][1024]
    const float* __restrict__ b0, const float* __restrict__ b1,
    const float* __restrict__ b2, int N) {
  constexpr int K = 768;
  constexpr int KT = K / 32;                   // 24 K-tiles
  __shared__ unsigned short As[3][128 * 32];   // row stride 32 el (64 B)
  __shared__ unsigned short Bs[3][128 * 32];

  const int tid = threadIdx.x;
  const int lane = tid & 63;
  const int w = tid >> 6;
  const int wrow = w >> 1, wcol = w & 1;
  const int l15 = lane & 15, quad = lane >> 4;

  // Bijective XCD swizzle: HW linear id (x-fastest) -> logical id so that
  // 8*per consecutive logical blocks (sharing A-tiles) sit on one XCD.
  const int gx = gridDim.x;
  const int nwg = gx * gridDim.y;                   // 2304 or 768; % 8 == 0
  const int hw = blockIdx.y * gx + blockIdx.x;
  const int per = nwg >> 3;
  const int lg = (hw & 7) * per + (hw >> 3);
  const int bx = lg % gx, by = lg / gx;
  const int i0 = by * 128, j0 = bx * 128;

  const unsigned short* ga = A + (size_t)(i0 + 32 * w + (lane >> 2)) * K + (lane & 3) * 8;
  const unsigned short* gb = Bt + (size_t)(j0 + 32 * w + (lane >> 2)) * K + (lane & 3) * 8;

  // stage K-tile kt2 into LDS buffer bufi (4 gld_lds per wave)
  auto stage = [&](int kt2, int bufi) {
    const unsigned short* pa = ga + kt2 * 32;
    const unsigned short* pb = gb + kt2 * 32;
    gld_lds16(pa, &As[bufi][(32 * w) * 32]);
    gld_lds16(pa + 16 * K, &As[bufi][(32 * w + 16) * 32]);
    gld_lds16(pb, &Bs[bufi][(32 * w) * 32]);
    gld_lds16(pb + 16 * K, &Bs[bufi][(32 * w + 16) * 32]);
  };

  float4v acc[4][4];
#pragma unroll
  for (int a = 0; a < 4; ++a)
#pragma unroll
    for (int b = 0; b < 4; ++b) acc[a][b] = float4v{0.f, 0.f, 0.f, 0.f};

  // prologue: 2 tiles in flight; wait for tile 0 only (vmcnt(4))
  stage(0, 0);
  stage(1, 1);
  asm volatile("s_waitcnt vmcnt(4)" ::: "memory");
  __builtin_amdgcn_s_barrier();
  __builtin_amdgcn_sched_barrier(0);

#pragma unroll 1
  for (int kt = 0; kt < KT; ++kt) {
    const int cur = kt % 3;
    if (kt + 2 < KT) stage(kt + 2, (kt + 2) % 3);  // 2-deep prefetch

    short8 af[4], bfr[4];
#pragma unroll
    for (int a = 0; a < 4; ++a)
      af[a] = *(const short8*)&As[cur][(wrow * 64 + a * 16 + l15) * 32 + quad * 8];
#pragma unroll
    for (int b = 0; b < 4; ++b)
      bfr[b] = *(const short8*)&Bs[cur][(wcol * 64 + b * 16 + l15) * 32 + quad * 8];
#pragma unroll
    for (int a = 0; a < 4; ++a)
#pragma unroll
      for (int b = 0; b < 4; ++b)
        acc[a][b] = __builtin_amdgcn_mfma_f32_16x16x32_bf16(af[a], bfr[b], acc[a][b], 0, 0, 0);

    // gate tile kt+1 residency; keep tile kt+2's 4 loads in flight
    if (kt + 2 < KT) {
      asm volatile("s_waitcnt vmcnt(4)" ::: "memory");
      __builtin_amdgcn_s_barrier();
      __builtin_amdgcn_sched_barrier(0);
    } else if (kt + 1 < KT) {
      asm volatile("s_waitcnt vmcnt(0)" ::: "memory");
      __builtin_amdgcn_s_barrier();
      __builtin_amdgcn_sched_barrier(0);
    }
    // last iter: no barrier; epilogue touches no LDS
  }

  const int sel = j0 / 768;
  const float* bp = (sel == 0) ? b0 : ((sel == 1) ? b1 : b2);
#pragma unroll
  for (int a = 0; a < 4; ++a) {
    const int row0 = i0 + wrow * 64 + a * 16 + quad * 4;
#pragma unroll
    for (int b = 0; b < 4; ++b) {
      const int col = j0 + wcol * 64 + b * 16 + l15;
      const float bias = bp[col - sel * 768];
      if (OUT_BF16 && sel == 2) {
        // V block -> transposed store into Vt.
        const int tb = row0 >> 10;
        const int n0 = row0 & 1023;            // multiple of 4 -> 8B aligned
        const int hd = col - 1536;             // h*64 + d
        const float v0 = acc[a][b][0] + bias;
        const float v1 = acc[a][b][1] + bias;
        const float v2 = acc[a][b][2] + bias;
        const float v3 = acc[a][b][3] + bias;
        uint2 u;
        u.x = (unsigned int)f2bf(v0) | ((unsigned int)f2bf(v1) << 16);
        u.y = (unsigned int)f2bf(v2) | ((unsigned int)f2bf(v3) << 16);
        *(uint2*)&Vt[((size_t)(tb * 768 + hd)) * 1024 + n0] = u;
      } else {
#pragma unroll
        for (int r = 0; r < 4; ++r) {
          const float v = acc[a][b][r] + bias;
          if (OUT_BF16)
            Cb[(size_t)(row0 + r) * N + col] = f2bf(v);
          else
            Cf[(size_t)(row0 + r) * N + col] = v;
        }
      }
    }
  }
}

// ---------------------------------------------------------------------------
// Attention v12. Grid (tbh=192, qt=4); 256 thr = 4 waves; wave = 64 q (2x32).
// Double-buffered K/V LDS, ONE lgkm-only barrier per kv-tile (v9 structure).
// P-pack path uses v_cvt_pk_bf16_f32 (1 VALU) instead of pkbf (3 VALU):
// r8 counters showed attn VALU-bound (VALUBusy 41.5 vs MfmaUtil 19.3).
__global__ __launch_bounds__(256) void attn32(
    const unsigned short* __restrict__ qkv,  // [16384, 2304] bf16
    const unsigned short* __restrict__ vt,   // [(tbh)*64 + d][1024] bf16
    unsigned short* __restrict__ ctx) {      // [16384, 768] bf16
  __shared__ unsigned short Ks[2][64 * 72];  // [buf][kv_local][d], padded
  __shared__ unsigned short Vs[2][64 * 72];  // [buf][d][kv_local], padded

  const int tbh = blockIdx.x;                // same-head blocks: ids 192 apart
  const int qt = blockIdx.y;                 // -> same XCD (192 % 8 == 0)
  const int tb = tbh / 12, h = tbh % 12;
  const int tid = threadIdx.x, lane = tid & 63, w = tid >> 6;
  const int l31 = lane & 31, hl = lane >> 5;

  // ---- Q fragments: one-time scattered global loads ----
  short8 qf[2][4];   // [qs][kc]: B-op: lane holds Q[q=.. +l31][kc*16+hl*8+j]
#pragma unroll
  for (int qs = 0; qs < 2; ++qs) {
    const unsigned short* qp =
        qkv + (size_t)(tb * 1024 + qt * 256 + w * 64 + qs * 32 + l31) * 2304 +
        h * 64 + hl * 8;
#pragma unroll
    for (int kc = 0; kc < 4; ++kc) qf[qs][kc] = *(const short8*)(qp + kc * 16);
  }

  // ---- staging: 256 thr cover 64 rows x 8 chunks of 16B, 2 rows/thread ----
  const int srow = tid >> 3;   // 0..31 (and +32)
  const int sblk = tid & 7;
  const unsigned short* kcol =
      qkv + (size_t)(tb * 1024) * 2304 + 768 + h * 64 + sblk * 8;
  const unsigned short* vcol = vt + ((size_t)tbh * 64 + srow) * 1024 + sblk * 8;
  uint4 kr0, kr1, vr0, vr1;
  auto loadKV = [&](int kv) {
    const unsigned short* kp = kcol + (size_t)(kv * 64 + srow) * 2304;
    kr0 = *(const uint4*)kp;
    kr1 = *(const uint4*)(kp + 32 * 2304);
    const unsigned short* vp = vcol + kv * 64;
    vr0 = *(const uint4*)vp;
    vr1 = *(const uint4*)(vp + 32 * 1024);
  };

  float16v octx[2][2];   // [qs][dt]; C: row=d_local, col=q=l31
#pragma unroll
  for (int qs = 0; qs < 2; ++qs)
#pragma unroll
    for (int dt = 0; dt < 2; ++dt)
#pragma unroll
      for (int i = 0; i < 16; ++i) octx[qs][dt][i] = 0.f;
  float den[2] = {0.f, 0.f};

  loadKV(0);

#pragma unroll 1
  for (int kv = 0; kv < 16; ++kv) {
    const int cur = kv & 1;
    // stage tile kv into buf[cur]; reg deps make HW wait on kv's loads only
    *(uint4*)&Ks[cur][srow * 72 + sblk * 8] = kr0;
    *(uint4*)&Ks[cur][(srow + 32) * 72 + sblk * 8] = kr1;
    *(uint4*)&Vs[cur][srow * 72 + sblk * 8] = vr0;
    *(uint4*)&Vs[cur][(srow + 32) * 72 + sblk * 8] = vr1;
    if (kv < 15) loadKV(kv + 1);   // in flight across barrier + compute
    asm volatile("s_waitcnt lgkmcnt(0)" ::: "memory");  // my ds_writes done
    __builtin_amdgcn_s_barrier();                       // no vmcnt drain
    __builtin_amdgcn_sched_barrier(0);

#pragma unroll
    for (int qs = 0; qs < 2; ++qs) {
      // S^T = K.Q^T, then relu+den+pack (C: col=q=l31, row=kv=4hl+(r)+8g+32mt)
      unsigned int pk[2][8];   // [mt][g*2+p]
#pragma unroll
      for (int mt = 0; mt < 2; ++mt) {
        float16v st;
#pragma unroll
        for (int i = 0; i < 16; ++i) st[i] = 0.f;
#pragma unroll
        for (int kc = 0; kc < 4; ++kc) {
          short8 kf =
              *(const short8*)&Ks[cur][(mt * 32 + l31) * 72 + kc * 16 + hl * 8];
          st = __builtin_amdgcn_mfma_f32_32x32x16_bf16(kf, qf[qs][kc], st, 0, 0, 0);
        }
#pragma unroll
        for (int g = 0; g < 4; ++g) {
          float v0 = st[4 * g + 0]; v0 = v0 > 0.f ? v0 : 0.f;
          float v1 = st[4 * g + 1]; v1 = v1 > 0.f ? v1 : 0.f;
          float v2 = st[4 * g + 2]; v2 = v2 > 0.f ? v2 : 0.f;
          float v3 = st[4 * g + 3]; v3 = v3 > 0.f ? v3 : 0.f;
          den[qs] += (v0 + v1) + (v2 + v3);
          pk[mt][g * 2 + 0] = cvtpk(v0, v1);   // 1 VALU (was 3)
          pk[mt][g * 2 + 1] = cvtpk(v2, v3);
        }
      }
      // C-layout -> PV B-operand layout entirely in registers.
#pragma unroll
      for (int kc = 0; kc < 4; ++kc) {
        const int mt = kc >> 1, gb = (kc & 1) * 2;
        unsigned int a0 = pk[mt][gb * 2 + 0], b0 = pk[mt][gb * 2 + 2];
        unsigned int a1 = pk[mt][gb * 2 + 1], b1 = pk[mt][gb * 2 + 3];
        asm("v_permlane32_swap_b32 %0, %1" : "+v"(a0), "+v"(b0));
        asm("v_permlane32_swap_b32 %0, %1" : "+v"(a1), "+v"(b1));
        union { unsigned int u[4]; short8 s; } pf;
        pf.u[0] = a0; pf.u[1] = a1; pf.u[2] = b0; pf.u[3] = b1;
#pragma unroll
        for (int dt = 0; dt < 2; ++dt) {
          short8 vb =
              *(const short8*)&Vs[cur][(dt * 32 + l31) * 72 + kc * 16 + hl * 8];
          octx[qs][dt] = __builtin_amdgcn_mfma_f32_32x32x16_bf16(
              vb, pf.s, octx[qs][dt], 0, 0, 0);
        }
      }
    }
    // no trailing barrier: buf[cur] next overwritten at kv+2, behind the
    // barrier of kv+1 whose lgkmcnt(0) drains this iter's ds_reads.
  }

  // ---- normalize + store; lane l31 owns q, all in registers ----
#pragma unroll
  for (int qs = 0; qs < 2; ++qs) {
    float d = den[qs] + __shfl_xor(den[qs], 32);
    const float sc = 1.f / (d + 8e-6f);   // folded 1/sqrt(64) scaling
    const size_t qrow = (size_t)(tb * 1024 + qt * 256 + w * 64 + qs * 32 + l31);
#pragma unroll
    for (int dt = 0; dt < 2; ++dt)
#pragma unroll
      for (int g = 0; g < 4; ++g) {
        const float v0 = octx[qs][dt][4 * g + 0] * sc;
        const float v1 = octx[qs][dt][4 * g + 1] * sc;
        const float v2 = octx[qs][dt][4 * g + 2] * sc;
        const float v3 = octx[qs][dt][4 * g + 3] * sc;
        uint2 u;
        u.x = cvtpk(v0, v1);
        u.y = cvtpk(v2, v3);
        *(uint2*)&ctx[qrow * 768 + h * 64 + dt * 32 + g * 8 + hl * 4] = u;
      }
  }
}

// ---------------------------------------------------------------------------
extern "C" void kernel_launch(void* const* d_in, const int* in_sizes, int n_in,
                              void* d_out, int out_size, void* d_ws, size_t ws_size,
                              hipStream_t stream) {
  const float* x  = (const float*)d_in[0];
  const float* Wq = (const float*)d_in[1];
  const float* bq = (const float*)d_in[2];
  const float* Wk = (const float*)d_in[3];
  const float* bk = (const float*)d_in[4];
  const float* Wv = (const float*)d_in[5];
  const float* bv = (const float*)d_in[6];
  const float* Wo = (const float*)d_in[7];
  const float* bo = (const float*)d_in[8];
  float* out = (float*)d_out;

  char* ws = (char*)d_ws;
  // workspace layout (bytes); CTX aliases XBF (XBF dead after QKV GEMM)
  unsigned short* XBF  = (unsigned short*)(ws);                  // 25165824 B
  unsigned short* CTX  = (unsigned short*)(ws);                  // alias
  unsigned short* WQKV = (unsigned short*)(ws + 25165824);       //  3538944 B
  unsigned short* WOb  = (unsigned short*)(ws + 28704768);       //  1179648 B
  unsigned short* QKV  = (unsigned short*)(ws + 29884416);       // 75497472 B
  unsigned short* VT   = (unsigned short*)(ws + 105381888);      // 25165824 B
  // total: 130547712 B

  cast_all<<<14592, 256, 0, stream>>>(x, Wq, Wk, Wv, Wo, XBF, WQKV, WOb);

  gemm_bt<true><<<dim3(18, 128), 256, 0, stream>>>(XBF, WQKV, QKV, nullptr, VT,
                                                   bq, bk, bv, 2304);
  attn32<<<dim3(192, 4), 256, 0, stream>>>(QKV, VT, CTX);
  gemm_bt<false><<<dim3(6, 128), 256, 0, stream>>>(CTX, WOb, nullptr, out,
                                                   nullptr, bo, bo, bo, 768);
}